// Round 1
// baseline (1885.426 us; speedup 1.0000x reference)
//
#include <hip/hip_runtime.h>
#include <math.h>

// dims
constexpr int Nn = 1024, Bb = 8, HIDc = 256, Hh = 8, DHc = 32;

// ---------------------------------------------------------------------------
// Generic dense kernel: out = epilogue( X @ W + bias )
// 8 tokens per block, 256 threads. X rows staged in LDS (broadcast reads).
// EPI: 0 = LN(resid + y), 1 = ReLU store, 2 = QKV split to (B,H,N,DH), 3 = LN(y)
// ---------------------------------------------------------------------------
template<int K, int M, int EPI, bool ADD_PE>
__global__ __launch_bounds__(256)
void dense_k(const float* __restrict__ X, const float* __restrict__ W,
             const float* __restrict__ bias, const float* __restrict__ resid,
             const float* __restrict__ gamma, const float* __restrict__ beta,
             float* __restrict__ out0, float* __restrict__ out1, float* __restrict__ out2)
{
    __shared__ float xs[8][K];
    __shared__ float red[8];
    const int tid = threadIdx.x;
    const int t0 = blockIdx.x * 8;

    // stage 8 input rows (optionally add sinusoidal PE)
    for (int t = 0; t < 8; ++t) {
        for (int kk = tid; kk < K; kk += 256) {
            float vv = X[(size_t)(t0 + t) * K + kk];
            if (ADD_PE) {
                int n = (t0 + t) >> 3;  // token / B
                float e = (float)((kk >> 1) * 2) * (1.0f / 256.0f);
                float freq = exp2f(-13.287712379549449f * e);  // 10000^-e
                float ang = (float)n * freq;
                vv += (kk & 1) ? cosf(ang) : sinf(ang);
            }
            xs[t][kk] = vv;
        }
    }
    __syncthreads();

    constexpr int G = M / 256;
    #pragma unroll
    for (int g = 0; g < G; ++g) {
        const int col = g * 256 + tid;
        float acc[8];
        const float bb = bias[col];
        #pragma unroll
        for (int t = 0; t < 8; ++t) acc[t] = bb;

        for (int kk = 0; kk < K; kk += 4) {
            const float w0 = W[(size_t)(kk + 0) * M + col];
            const float w1 = W[(size_t)(kk + 1) * M + col];
            const float w2 = W[(size_t)(kk + 2) * M + col];
            const float w3 = W[(size_t)(kk + 3) * M + col];
            #pragma unroll
            for (int t = 0; t < 8; ++t) {
                const float4 xv = *reinterpret_cast<const float4*>(&xs[t][kk]);
                float a = acc[t];
                a = fmaf(xv.x, w0, a);
                a = fmaf(xv.y, w1, a);
                a = fmaf(xv.z, w2, a);
                a = fmaf(xv.w, w3, a);
                acc[t] = a;
            }
        }

        if constexpr (EPI == 2) {
            // split into q/k/v with (B,H,N,DH) layout
            float* dst = (g == 0) ? out0 : ((g == 1) ? out1 : out2);
            const int h = tid >> 5, dh = tid & 31;
            #pragma unroll
            for (int t = 0; t < 8; ++t) {
                const int token = t0 + t;
                const int n = token >> 3, b = token & 7;
                dst[(((size_t)(b * Hh + h)) * Nn + n) * DHc + dh] = acc[t];
            }
        } else if constexpr (EPI == 1) {
            #pragma unroll
            for (int t = 0; t < 8; ++t)
                out0[(size_t)(t0 + t) * M + col] = fmaxf(acc[t], 0.0f);
        } else {
            // LayerNorm epilogue (M == 256, G == 1)
            const float gm = gamma[tid], bt = beta[tid];
            const int lane = tid & 63, wv = tid >> 6;
            float val[8];
            #pragma unroll
            for (int t = 0; t < 8; ++t) {
                val[t] = acc[t];
                if constexpr (EPI == 0) val[t] += resid[(size_t)(t0 + t) * 256 + tid];
            }
            for (int t = 0; t < 8; ++t) {
                float s1 = val[t], s2 = val[t] * val[t];
                #pragma unroll
                for (int off = 32; off > 0; off >>= 1) {
                    s1 += __shfl_down(s1, off);
                    s2 += __shfl_down(s2, off);
                }
                if (lane == 0) { red[wv] = s1; red[4 + wv] = s2; }
                __syncthreads();
                const float mu = (red[0] + red[1] + red[2] + red[3]) * (1.0f / 256.0f);
                const float ms = (red[4] + red[5] + red[6] + red[7]) * (1.0f / 256.0f);
                const float rv = rsqrtf(ms - mu * mu + 1e-5f);
                out0[(size_t)(t0 + t) * 256 + tid] = (val[t] - mu) * rv * gm + bt;
                __syncthreads();
            }
        }
    }
}

// ---------------------------------------------------------------------------
// Masked flash attention. Block = one (b,h) x 32 queries; 4 waves x 8 rows.
// Online softmax over 16 chunks of 64 keys. K row per lane in registers,
// V chunk in padded LDS. Mask derived from dist on the fly.
// Output written directly in (N,B,HID) layout.
// ---------------------------------------------------------------------------
__global__ __launch_bounds__(256)
void attn_k(const float* __restrict__ Q, const float* __restrict__ Kb,
            const float* __restrict__ Vb, const int* __restrict__ dist,
            float* __restrict__ O)
{
    __shared__ float Vt[64][33];   // +1 pad: kills bank conflicts
    __shared__ float qs[32][32];
    const int tid = threadIdx.x;
    const int lane = tid & 63;
    const int wv = tid >> 6;
    const int bh = blockIdx.y;
    const int b = bh >> 3, h = bh & 7;
    const int q0 = blockIdx.x * 32;

    const float* Qp = Q + ((size_t)bh * Nn + q0) * DHc;
    for (int i = tid; i < 32 * 32; i += 256) qs[i >> 5][i & 31] = Qp[i];

    float accR[8], Mst[8], Lst[8];
    #pragma unroll
    for (int r = 0; r < 8; ++r) { accR[r] = 0.0f; Mst[r] = -INFINITY; Lst[r] = 0.0f; }
    const int r_rep = lane >> 5;   // which half of the wave (key split)
    const int dh = lane & 31;
    const int* distB = dist + (size_t)b * Nn * Nn;
    const float scale = 0.17677669529663687f;  // 1/sqrt(32)

    for (int c = 0; c < 16; ++c) {
        __syncthreads();
        const float* Vp = Vb + ((size_t)bh * Nn + c * 64) * DHc;
        for (int i = tid; i < 64 * 32; i += 256) Vt[i >> 5][i & 31] = Vp[i];
        // this lane's K row (key m = c*64 + lane), 32 floats in registers
        float4 kr[8];
        const float4* kp = reinterpret_cast<const float4*>(Kb + ((size_t)bh * Nn + c * 64 + lane) * DHc);
        #pragma unroll
        for (int j = 0; j < 8; ++j) kr[j] = kp[j];
        __syncthreads();

        #pragma unroll 1
        for (int r = 0; r < 8; ++r) {
            const int qi = q0 + wv * 8 + r;
            const float* qrow = qs[wv * 8 + r];
            float s = 0.0f;
            #pragma unroll
            for (int j = 0; j < 8; ++j) {
                s = fmaf(qrow[4 * j + 0], kr[j].x, s);
                s = fmaf(qrow[4 * j + 1], kr[j].y, s);
                s = fmaf(qrow[4 * j + 2], kr[j].z, s);
                s = fmaf(qrow[4 * j + 3], kr[j].w, s);
            }
            s *= scale;
            const int d = distB[(size_t)qi * Nn + c * 64 + lane];
            const bool allowed = (h < 2) ? (d == 1) : ((h < 6) ? (d >= 1) : true);
            s = allowed ? s : -INFINITY;

            // wave max of this chunk
            float mx = s;
            #pragma unroll
            for (int off = 32; off > 0; off >>= 1) mx = fmaxf(mx, __shfl_xor(mx, off));
            const float Mnew = fmaxf(Mst[r], mx);
            // alpha: guard Mnew==-inf (fully-masked so far); exp(-inf)=0 handles Mst=-inf
            const float alpha = (Mnew == -INFINITY) ? 1.0f : __expf(Mst[r] - Mnew);
            const float p = (s == -INFINITY) ? 0.0f : __expf(s - Mnew);
            float ps = p;
            #pragma unroll
            for (int off = 32; off > 0; off >>= 1) ps += __shfl_xor(ps, off);
            Lst[r] = Lst[r] * alpha + ps;
            Mst[r] = Mnew;

            float a = accR[r] * alpha;
            // this lane accumulates keys of its half (r_rep*32 .. +31) into dim dh
            #pragma unroll
            for (int jj = 0; jj < 32; ++jj) {
                const float pv = __shfl(p, r_rep * 32 + jj);
                a = fmaf(pv, Vt[r_rep * 32 + jj][dh], a);
            }
            accR[r] = a;
        }
    }

    // combine the two key-halves and normalize; write (N,B,HID)
    #pragma unroll
    for (int r = 0; r < 8; ++r) {
        const float o2 = accR[r] + __shfl_xor(accR[r], 32);
        const float invl = 1.0f / Lst[r];
        const int qi = q0 + wv * 8 + r;
        if (lane < 32) {
            O[((size_t)qi * Bb + b) * HIDc + h * DHc + dh] = o2 * invl;
        }
    }
}

// ---------------------------------------------------------------------------
// Final: y = x[0] (tokens b=0..7), batch-norm over B, scale/shift.
// ---------------------------------------------------------------------------
__global__ __launch_bounds__(256)
void final_bn(const float* __restrict__ x, const float* __restrict__ g,
              const float* __restrict__ bta, float* __restrict__ out)
{
    const int d = threadIdx.x;
    float y[8]; float mu = 0.0f;
    #pragma unroll
    for (int i = 0; i < 8; ++i) { y[i] = x[i * 256 + d]; mu += y[i]; }
    mu *= 0.125f;
    float var = 0.0f;
    #pragma unroll
    for (int i = 0; i < 8; ++i) { const float dd = y[i] - mu; var += dd * dd; }
    var *= 0.125f;
    const float r = rsqrtf(var + 1e-5f);
    const float gg = g[d], bb = bta[d];
    #pragma unroll
    for (int i = 0; i < 8; ++i) out[i * 256 + d] = (y[i] - mu) * r * gg + bb;
}

extern "C" void kernel_launch(void* const* d_in, const int* in_sizes, int n_in,
                              void* d_out, int out_size, void* d_ws, size_t ws_size,
                              hipStream_t stream)
{
    const float* nodes   = (const float*)d_in[0];
    const int*   dist    = (const int*)  d_in[1];
    const float* W_in    = (const float*)d_in[2];
    const float* b_in    = (const float*)d_in[3];
    const float* ln_in_g = (const float*)d_in[4];
    const float* ln_in_b = (const float*)d_in[5];
    const float* Wqkv    = (const float*)d_in[6];
    const float* bqkv    = (const float*)d_in[7];
    const float* Wo      = (const float*)d_in[8];
    const float* bo      = (const float*)d_in[9];
    const float* ln1_g   = (const float*)d_in[10];
    const float* ln1_b   = (const float*)d_in[11];
    const float* W1      = (const float*)d_in[12];
    const float* b1      = (const float*)d_in[13];
    const float* W2      = (const float*)d_in[14];
    const float* b2      = (const float*)d_in[15];
    const float* ln2_g   = (const float*)d_in[16];
    const float* ln2_b   = (const float*)d_in[17];
    const float* bn_g    = (const float*)d_in[18];
    const float* bn_b    = (const float*)d_in[19];

    // workspace layout (floats): x | q | k | v | o   (h1 aliases q+k, dead then)
    float* ws   = (float*)d_ws;
    float* x    = ws;
    float* q    = ws + 1 * 2097152;
    float* kbuf = ws + 2 * 2097152;
    float* vbuf = ws + 3 * 2097152;
    float* obuf = ws + 4 * 2097152;
    float* h1   = q;  // 8192*512 floats, overlaps q+k (both dead during FFN)

    // x = LN((nodes + PE) @ W_in + b_in)
    dense_k<256, 256, 3, true><<<1024, 256, 0, stream>>>(
        nodes, W_in, b_in, nullptr, ln_in_g, ln_in_b, x, nullptr, nullptr);

    for (int l = 0; l < 2; ++l) {
        // qkv
        dense_k<256, 768, 2, false><<<1024, 256, 0, stream>>>(
            x, Wqkv + (size_t)l * 256 * 768, bqkv + l * 768,
            nullptr, nullptr, nullptr, q, kbuf, vbuf);
        // attention -> obuf in (N,B,HID)
        attn_k<<<dim3(32, 64), 256, 0, stream>>>(q, kbuf, vbuf, dist, obuf);
        // x = LN(x + obuf @ Wo + bo)
        dense_k<256, 256, 0, false><<<1024, 256, 0, stream>>>(
            obuf, Wo + (size_t)l * 256 * 256, bo + l * 256,
            x, ln1_g + l * 256, ln1_b + l * 256, x, nullptr, nullptr);
        // h1 = relu(x @ W1 + b1)
        dense_k<256, 512, 1, false><<<1024, 256, 0, stream>>>(
            x, W1 + (size_t)l * 256 * 512, b1 + l * 512,
            nullptr, nullptr, nullptr, h1, nullptr, nullptr);
        // x = LN(x + h1 @ W2 + b2)
        dense_k<512, 256, 0, false><<<1024, 256, 0, stream>>>(
            h1, W2 + (size_t)l * 512 * 256, b2 + l * 256,
            x, ln2_g + l * 256, ln2_b + l * 256, x, nullptr, nullptr);
    }

    final_bn<<<1, 256, 0, stream>>>(x, bn_g, bn_b, (float*)d_out);
}

// Round 2
// 705.493 us; speedup vs baseline: 2.6725x; 2.6725x over previous
//
#include <hip/hip_runtime.h>
#include <math.h>

// dims
constexpr int Nn = 1024, Bb = 8, HIDc = 256, Hh = 8, DHc = 32;

typedef __bf16 bf16x8 __attribute__((ext_vector_type(8)));
typedef float  f32x4  __attribute__((ext_vector_type(4)));

// ---------------------------------------------------------------------------
// Generic dense kernel: out = epilogue( X @ W + bias )
// 8 tokens per block (= all 8 batch entries of one n), 256 threads.
// EPI: 0 = LN(resid + y), 1 = ReLU store, 2 = QKV split -> bf16 (q scaled,
//      k rows, v transposed), 3 = LN(y)
// ---------------------------------------------------------------------------
template<int K, int M, int EPI, bool ADD_PE>
__global__ __launch_bounds__(256)
void dense_k(const float* __restrict__ X, const float* __restrict__ W,
             const float* __restrict__ bias, const float* __restrict__ resid,
             const float* __restrict__ gamma, const float* __restrict__ beta,
             float* __restrict__ out0, float* __restrict__ out1, float* __restrict__ out2)
{
    __shared__ float xs[8][K];
    __shared__ float red[8];
    const int tid = threadIdx.x;
    const int t0 = blockIdx.x * 8;

    // stage 8 input rows (optionally add sinusoidal PE)
    for (int t = 0; t < 8; ++t) {
        for (int kk = tid; kk < K; kk += 256) {
            float vv = X[(size_t)(t0 + t) * K + kk];
            if (ADD_PE) {
                int n = (t0 + t) >> 3;  // token / B
                float e = (float)((kk >> 1) * 2) * (1.0f / 256.0f);
                float freq = exp2f(-13.287712379549449f * e);  // 10000^-e
                float ang = (float)n * freq;
                vv += (kk & 1) ? cosf(ang) : sinf(ang);
            }
            xs[t][kk] = vv;
        }
    }
    __syncthreads();

    constexpr int G = M / 256;
    #pragma unroll
    for (int g = 0; g < G; ++g) {
        const int col = g * 256 + tid;
        float acc[8];
        const float bb = bias[col];
        #pragma unroll
        for (int t = 0; t < 8; ++t) acc[t] = bb;

        for (int kk = 0; kk < K; kk += 4) {
            const float w0 = W[(size_t)(kk + 0) * M + col];
            const float w1 = W[(size_t)(kk + 1) * M + col];
            const float w2 = W[(size_t)(kk + 2) * M + col];
            const float w3 = W[(size_t)(kk + 3) * M + col];
            #pragma unroll
            for (int t = 0; t < 8; ++t) {
                const float4 xv = *reinterpret_cast<const float4*>(&xs[t][kk]);
                float a = acc[t];
                a = fmaf(xv.x, w0, a);
                a = fmaf(xv.y, w1, a);
                a = fmaf(xv.z, w2, a);
                a = fmaf(xv.w, w3, a);
                acc[t] = a;
            }
        }

        if constexpr (EPI == 2) {
            // q scaled by 1/sqrt(32); q,k as (B,H,N,DH) bf16; v as (B,H,DH,N) bf16
            const int h = tid >> 5, dh = tid & 31;
            #pragma unroll
            for (int t = 0; t < 8; ++t) {
                const int token = t0 + t;
                const int n = token >> 3, b2 = token & 7;
                float v = acc[t];
                if (g == 0) v *= 0.17677669529663687f;
                const __bf16 bv = (__bf16)v;
                if (g == 0)
                    ((__bf16*)out0)[(((size_t)(b2 * Hh + h)) * Nn + n) * DHc + dh] = bv;
                else if (g == 1)
                    ((__bf16*)out1)[(((size_t)(b2 * Hh + h)) * Nn + n) * DHc + dh] = bv;
                else
                    ((__bf16*)out2)[(((size_t)(b2 * Hh + h)) * DHc + dh) * Nn + n] = bv;
            }
        } else if constexpr (EPI == 1) {
            #pragma unroll
            for (int t = 0; t < 8; ++t)
                out0[(size_t)(t0 + t) * M + col] = fmaxf(acc[t], 0.0f);
        } else {
            // LayerNorm epilogue (M == 256, G == 1)
            const float gm = gamma[tid], bt = beta[tid];
            const int lane = tid & 63, wv = tid >> 6;
            float val[8];
            #pragma unroll
            for (int t = 0; t < 8; ++t) {
                val[t] = acc[t];
                if constexpr (EPI == 0) val[t] += resid[(size_t)(t0 + t) * 256 + tid];
            }
            for (int t = 0; t < 8; ++t) {
                float s1 = val[t], s2 = val[t] * val[t];
                #pragma unroll
                for (int off = 32; off > 0; off >>= 1) {
                    s1 += __shfl_down(s1, off);
                    s2 += __shfl_down(s2, off);
                }
                if (lane == 0) { red[wv] = s1; red[4 + wv] = s2; }
                __syncthreads();
                const float mu = (red[0] + red[1] + red[2] + red[3]) * (1.0f / 256.0f);
                const float ms = (red[4] + red[5] + red[6] + red[7]) * (1.0f / 256.0f);
                const float rv = rsqrtf(ms - mu * mu + 1e-5f);
                out0[(size_t)(t0 + t) * 256 + tid] = (val[t] - mu) * rv * gm + bt;
                __syncthreads();
            }
        }
    }
}

// ---------------------------------------------------------------------------
// Mask precompute: dist (B,N,N) int32 -> byte codes, permuted within each
// 64-key group to match MFMA column layout: key = c*64 + t*16 + col is
// stored at c*64 + col*4 + t, so a lane's 4 tile-bytes are one uchar4.
// bit0 = (d==1) short-allowed, bit1 = (d>=1) long-allowed.
// ---------------------------------------------------------------------------
__global__ __launch_bounds__(256)
void mask_k(const int* __restrict__ dist, unsigned char* __restrict__ mb)
{
    const size_t idx = (size_t)blockIdx.x * 256 + threadIdx.x;
    const int d = dist[idx];
    const unsigned char code = (unsigned char)((d == 1 ? 1 : 0) | (d >= 1 ? 2 : 0));
    const int k = (int)(idx & 1023);
    const int kp = (k & ~63) | ((k & 15) << 2) | ((k >> 4) & 3);
    mb[(idx & ~(size_t)1023) | (size_t)kp] = code;
}

// ---------------------------------------------------------------------------
// MFMA flash attention. Block = one (b,h) x 64 queries (4 waves x 16 q).
// No barriers: K/V fragments read straight from global (L2-resident),
// P round-trips through wave-private LDS (C-layout -> A-layout).
// ---------------------------------------------------------------------------
__global__ __launch_bounds__(256)
void attn_mfma(const __bf16* __restrict__ Qb, const __bf16* __restrict__ Kb,
               const __bf16* __restrict__ Vb, const unsigned char* __restrict__ MB,
               float* __restrict__ O)
{
    __shared__ __bf16 pbuf[4][16][72];   // 72: 16B-aligned rows, conflict-free b128
    const int tid = threadIdx.x;
    const int lane = tid & 63;
    const int wv = tid >> 6;
    const int col = lane & 15;
    const int quad = lane >> 4;
    const int bh = blockIdx.y;
    const int b = bh >> 3, h = bh & 7;
    const int q0 = blockIdx.x * 64 + wv * 16;   // this wave's first query
    const int hbit = (h < 2) ? 1 : (h < 6) ? 2 : 0;

    // Q fragment: A[m=col][k=quad*8+j] (q pre-scaled by 1/sqrt(DH))
    const bf16x8 qf = *(const bf16x8*)(Qb + ((size_t)bh * Nn + q0 + col) * DHc + quad * 8);

    f32x4 O0 = {0.f, 0.f, 0.f, 0.f}, O1 = {0.f, 0.f, 0.f, 0.f};
    float M[4], L[4];
    #pragma unroll
    for (int r = 0; r < 4; ++r) { M[r] = -INFINITY; L[r] = 0.0f; }

    const unsigned char* mrow = MB + ((size_t)b << 20) + col * 4;
    __bf16* pw = &pbuf[wv][0][0];
    const __bf16* prd = &pbuf[wv][col][0];
    const f32x4 zf = {0.f, 0.f, 0.f, 0.f};

    for (int c = 0; c < 16; ++c) {
        // --- QK^T: 4 tiles of 16 keys, B = K[key][dh] rows ---
        const __bf16* kp = Kb + ((size_t)bh * Nn + c * 64 + col) * DHc + quad * 8;
        f32x4 S[4];
        #pragma unroll
        for (int t = 0; t < 4; ++t) {
            const bf16x8 kf = *(const bf16x8*)(kp + (size_t)t * 16 * DHc);
            S[t] = __builtin_amdgcn_mfma_f32_16x16x32_bf16(qf, kf, zf, 0, 0, 0);
        }
        // --- mask ---
        if (hbit) {
            #pragma unroll
            for (int r = 0; r < 4; ++r) {
                const int q = q0 + quad * 4 + r;
                const uchar4 mk = *(const uchar4*)(mrow + ((size_t)q << 10) + c * 64);
                if (!(mk.x & hbit)) S[0][r] = -INFINITY;
                if (!(mk.y & hbit)) S[1][r] = -INFINITY;
                if (!(mk.z & hbit)) S[2][r] = -INFINITY;
                if (!(mk.w & hbit)) S[3][r] = -INFINITY;
            }
        }
        // --- online softmax (row q = quad*4+r; 16-lane groups share a row) ---
        float alpha[4];
        #pragma unroll
        for (int r = 0; r < 4; ++r) {
            float mx = fmaxf(fmaxf(S[0][r], S[1][r]), fmaxf(S[2][r], S[3][r]));
            mx = fmaxf(mx, __shfl_xor(mx, 1));
            mx = fmaxf(mx, __shfl_xor(mx, 2));
            mx = fmaxf(mx, __shfl_xor(mx, 4));
            mx = fmaxf(mx, __shfl_xor(mx, 8));
            const float Mnew = fmaxf(M[r], mx);
            alpha[r] = (Mnew == -INFINITY) ? 1.0f : __expf(M[r] - Mnew);
            float ps = 0.0f;
            #pragma unroll
            for (int t = 0; t < 4; ++t) {
                const float p = (S[t][r] == -INFINITY) ? 0.0f : __expf(S[t][r] - Mnew);
                S[t][r] = p;
                ps += p;
            }
            ps += __shfl_xor(ps, 1);
            ps += __shfl_xor(ps, 2);
            ps += __shfl_xor(ps, 4);
            ps += __shfl_xor(ps, 8);
            L[r] = L[r] * alpha[r] + ps;
            M[r] = Mnew;
        }
        // --- P -> LDS (A-layout round trip), rescale O ---
        #pragma unroll
        for (int r = 0; r < 4; ++r) {
            #pragma unroll
            for (int t = 0; t < 4; ++t)
                pw[(quad * 4 + r) * 72 + t * 16 + col] = (__bf16)S[t][r];
            O0[r] *= alpha[r];
            O1[r] *= alpha[r];
        }
        // --- PV: A = P[q][key], B = V^T[dh][key] rows (vb transposed) ---
        const __bf16* vp = Vb + ((size_t)bh * DHc) * Nn + c * 64 + quad * 8;
        #pragma unroll
        for (int kh = 0; kh < 2; ++kh) {
            const bf16x8 pf = *(const bf16x8*)(prd + kh * 32 + quad * 8);
            const bf16x8 v0 = *(const bf16x8*)(vp + (size_t)col * Nn + kh * 32);
            const bf16x8 v1 = *(const bf16x8*)(vp + (size_t)(col + 16) * Nn + kh * 32);
            O0 = __builtin_amdgcn_mfma_f32_16x16x32_bf16(pf, v0, O0, 0, 0, 0);
            O1 = __builtin_amdgcn_mfma_f32_16x16x32_bf16(pf, v1, O1, 0, 0, 0);
        }
    }
    // --- normalize + write (N,B,HID) fp32 ---
    #pragma unroll
    for (int r = 0; r < 4; ++r) {
        const float inv = 1.0f / L[r];
        const int q = q0 + quad * 4 + r;
        float* op = O + ((size_t)q * Bb + b) * HIDc + h * DHc + col;
        op[0]  = O0[r] * inv;
        op[16] = O1[r] * inv;
    }
}

// ---------------------------------------------------------------------------
// Final: y = x[0] (tokens b=0..7), batch-norm over B, scale/shift.
// ---------------------------------------------------------------------------
__global__ __launch_bounds__(256)
void final_bn(const float* __restrict__ x, const float* __restrict__ g,
              const float* __restrict__ bta, float* __restrict__ out)
{
    const int d = threadIdx.x;
    float y[8]; float mu = 0.0f;
    #pragma unroll
    for (int i = 0; i < 8; ++i) { y[i] = x[i * 256 + d]; mu += y[i]; }
    mu *= 0.125f;
    float var = 0.0f;
    #pragma unroll
    for (int i = 0; i < 8; ++i) { const float dd = y[i] - mu; var += dd * dd; }
    var *= 0.125f;
    const float r = rsqrtf(var + 1e-5f);
    const float gg = g[d], bb = bta[d];
    #pragma unroll
    for (int i = 0; i < 8; ++i) out[i * 256 + d] = (y[i] - mu) * r * gg + bb;
}

extern "C" void kernel_launch(void* const* d_in, const int* in_sizes, int n_in,
                              void* d_out, int out_size, void* d_ws, size_t ws_size,
                              hipStream_t stream)
{
    const float* nodes   = (const float*)d_in[0];
    const int*   dist    = (const int*)  d_in[1];
    const float* W_in    = (const float*)d_in[2];
    const float* b_in    = (const float*)d_in[3];
    const float* ln_in_g = (const float*)d_in[4];
    const float* ln_in_b = (const float*)d_in[5];
    const float* Wqkv    = (const float*)d_in[6];
    const float* bqkv    = (const float*)d_in[7];
    const float* Wo      = (const float*)d_in[8];
    const float* bo      = (const float*)d_in[9];
    const float* ln1_g   = (const float*)d_in[10];
    const float* ln1_b   = (const float*)d_in[11];
    const float* W1      = (const float*)d_in[12];
    const float* b1      = (const float*)d_in[13];
    const float* W2      = (const float*)d_in[14];
    const float* b2      = (const float*)d_in[15];
    const float* ln2_g   = (const float*)d_in[16];
    const float* ln2_b   = (const float*)d_in[17];
    const float* bn_g    = (const float*)d_in[18];
    const float* bn_b    = (const float*)d_in[19];

    // workspace (byte offsets):
    //   x    f32  0..8M      qb bf16 8M..12M     kb bf16 12M..16M
    //   vb  bf16 16M..20M    obuf f32 20M..28M   h1 f32 aliases 8M..24M
    //   mb  u8   28M..36M
    char* ws = (char*)d_ws;
    float*  x    = (float*)(ws);
    __bf16* qb   = (__bf16*)(ws + (8u  << 20));
    __bf16* kb   = (__bf16*)(ws + (12u << 20));
    __bf16* vb   = (__bf16*)(ws + (16u << 20));
    float*  obuf = (float*)(ws + (20u << 20));
    float*  h1   = (float*)(ws + (8u  << 20));  // aliases qb/kb/vb/obuf[0:4M] (dead)
    unsigned char* mb = (unsigned char*)(ws + (28u << 20));

    // packed permuted mask from dist (shared by both layers)
    mask_k<<<32768, 256, 0, stream>>>(dist, mb);

    // x = LN((nodes + PE) @ W_in + b_in)
    dense_k<256, 256, 3, true><<<1024, 256, 0, stream>>>(
        nodes, W_in, b_in, nullptr, ln_in_g, ln_in_b, x, nullptr, nullptr);

    for (int l = 0; l < 2; ++l) {
        // qkv -> bf16 q (scaled), k, v^T
        dense_k<256, 768, 2, false><<<1024, 256, 0, stream>>>(
            x, Wqkv + (size_t)l * 256 * 768, bqkv + l * 768,
            nullptr, nullptr, nullptr, (float*)qb, (float*)kb, (float*)vb);
        // attention -> obuf in (N,B,HID) fp32
        attn_mfma<<<dim3(16, 64), 256, 0, stream>>>(qb, kb, vb, mb, obuf);
        // x = LN(x + obuf @ Wo + bo)
        dense_k<256, 256, 0, false><<<1024, 256, 0, stream>>>(
            obuf, Wo + (size_t)l * 256 * 256, bo + l * 256,
            x, ln1_g + l * 256, ln1_b + l * 256, x, nullptr, nullptr);
        // h1 = relu(x @ W1 + b1)
        dense_k<256, 512, 1, false><<<1024, 256, 0, stream>>>(
            x, W1 + (size_t)l * 256 * 512, b1 + l * 512,
            nullptr, nullptr, nullptr, h1, nullptr, nullptr);
        // x = LN(x + h1 @ W2 + b2)
        dense_k<512, 256, 0, false><<<1024, 256, 0, stream>>>(
            h1, W2 + (size_t)l * 512 * 256, b2 + l * 256,
            x, ln2_g + l * 256, ln2_b + l * 256, x, nullptr, nullptr);
    }

    final_bn<<<1, 256, 0, stream>>>(x, bn_g, bn_b, (float*)d_out);
}

// Round 3
// 583.031 us; speedup vs baseline: 3.2338x; 1.2100x over previous
//
#include <hip/hip_runtime.h>
#include <math.h>

// dims
constexpr int Nn = 1024, Bb = 8, HIDc = 256, Hh = 8, DHc = 32;

typedef __bf16 bf16x8 __attribute__((ext_vector_type(8)));
typedef float  f32x4  __attribute__((ext_vector_type(4)));

// ---------------------------------------------------------------------------
// Weight convert+transpose: Wt[m][k] = bf16(W[k][m]) for all 9 weight mats.
// One launch; per-block segment lookup; 32x32 LDS tile transpose.
// ---------------------------------------------------------------------------
struct WCvtArgs {
    const float* src[9];
    int K[9], M[9], dstOff[9], tiles[9];
};

__global__ __launch_bounds__(256)
void wcvt_k(WCvtArgs a, __bf16* __restrict__ Wt)
{
    __shared__ float ts[32][33];
    int bid = blockIdx.x, i = 0;
    while (bid >= a.tiles[i]) { bid -= a.tiles[i]; ++i; }
    const int K = a.K[i], M = a.M[i];
    const int tilesM = M >> 5;
    const int m0 = (bid % tilesM) << 5, k0 = (bid / tilesM) << 5;
    const float* src = a.src[i];
    __bf16* dst = Wt + a.dstOff[i];
    const int tx = threadIdx.x & 31, ty = threadIdx.x >> 5;
    #pragma unroll
    for (int j = 0; j < 4; ++j) {
        const int row = ty + 8 * j;
        ts[row][tx] = src[(size_t)(k0 + row) * M + m0 + tx];
    }
    __syncthreads();
    #pragma unroll
    for (int j = 0; j < 4; ++j) {
        const int row = ty + 8 * j;
        dst[(size_t)(m0 + row) * K + k0 + tx] = (__bf16)ts[tx][row];
    }
}

// ---------------------------------------------------------------------------
// Mask precompute: dist (B,N,N) int32 -> 4-bit codes packed in ushort,
// one ushort per (b,q,chunk c,col): nibble t = code(key = c*64 + t*16 + col).
// bit0 = (d==1), bit1 = (d>=1).
// ---------------------------------------------------------------------------
__global__ __launch_bounds__(256)
void mask_k(const int* __restrict__ dist, unsigned short* __restrict__ mbu)
{
    const int idx = blockIdx.x * 256 + threadIdx.x;   // 2M entries
    const int col = idx & 15, c = (idx >> 4) & 15, q = (idx >> 8) & 1023, b = idx >> 18;
    const int* dp = dist + ((((size_t)b << 10) + q) << 10) + c * 64 + col;
    unsigned int us = 0;
    #pragma unroll
    for (int t = 0; t < 4; ++t) {
        const int d = dp[t * 16];
        const unsigned int code = (unsigned int)((d == 1 ? 1 : 0) | (d >= 1 ? 2 : 0));
        us |= code << (4 * t);
    }
    mbu[idx] = (unsigned short)us;
}

// ---------------------------------------------------------------------------
// Input prep: xinb = bf16(nodes + sinusoidal PE). Two elements per thread.
// ---------------------------------------------------------------------------
__global__ __launch_bounds__(256)
void xin_k(const float* __restrict__ nodes, __bf16* __restrict__ xinb)
{
    const int idx = blockIdx.x * 256 + threadIdx.x;   // 1M threads
    const int token = idx >> 7, k2 = (idx & 127) * 2;
    const int n = token >> 3;
    const float e = (float)k2 * (1.0f / 256.0f);
    const float freq = exp2f(-13.287712379549449f * e);   // 10000^-e
    const float ang = (float)n * freq;
    const float2 nd = *(const float2*)(nodes + (size_t)token * 256 + k2);
    __bf16 o0 = (__bf16)(nd.x + sinf(ang));
    __bf16 o1 = (__bf16)(nd.y + cosf(ang));
    __bf16* p = xinb + (size_t)token * 256 + k2;
    p[0] = o0; p[1] = o1;
}

// ---------------------------------------------------------------------------
// MFMA dense: out = epilogue( Xb @ Wt^T + bias ). Block = 2 waves x 16 rows.
// Wave computes 16 rows x 256 cols (16 tiles of 16x16x32), no LDS/barriers.
// EPI: 0 = LN(resid + y) -> fp32 + bf16   3 = LN(y) -> fp32 + bf16
//      1 = ReLU -> bf16 (M=512 via grid.y)
//      2 = QKV: grid.y = 0/1/2 -> q(scaled)/k/v^T, n-major row mapping
// ---------------------------------------------------------------------------
template<int K, int EPI>
__global__ __launch_bounds__(128)
void dense_mfma(const __bf16* __restrict__ Xb, const __bf16* __restrict__ Wt,
                const float* __restrict__ bias, const float* __restrict__ resid,
                const float* __restrict__ gamma, const float* __restrict__ beta,
                float* __restrict__ outf, __bf16* __restrict__ outb,
                __bf16* __restrict__ outb2, __bf16* __restrict__ outb3)
{
    const int tid = threadIdx.x;
    const int lane = tid & 63;
    const int wv = tid >> 6;          // 0..1
    const int col = lane & 15;
    const int quad = lane >> 4;
    const int cg = blockIdx.y;
    constexpr int NC = K / 32;

    int rowA, b = 0, n0 = 0;
    if constexpr (EPI == 2) {
        b = blockIdx.x & 7;
        n0 = (blockIdx.x >> 3) * 32 + wv * 16;
        rowA = (n0 + col) * 8 + b;
    } else {
        rowA = blockIdx.x * 32 + wv * 16 + col;
    }

    bf16x8 af[NC];
    #pragma unroll
    for (int kc = 0; kc < NC; ++kc)
        af[kc] = *(const bf16x8*)(Xb + (size_t)rowA * K + kc * 32 + quad * 8);

    f32x4 acc[16];
    #pragma unroll
    for (int t = 0; t < 16; ++t) acc[t] = (f32x4){0.f, 0.f, 0.f, 0.f};

    const __bf16* wbase = Wt + ((size_t)(cg * 256 + col)) * K + quad * 8;
    #pragma unroll
    for (int t = 0; t < 16; ++t) {
        const __bf16* wp = wbase + (size_t)t * 16 * K;
        #pragma unroll
        for (int kc = 0; kc < NC; ++kc) {
            const bf16x8 bf = *(const bf16x8*)(wp + kc * 32);
            acc[t] = __builtin_amdgcn_mfma_f32_16x16x32_bf16(af[kc], bf, acc[t], 0, 0, 0);
        }
    }

    if constexpr (EPI == 0 || EPI == 3) {
        float bb[16], gm[16], bt[16];
        #pragma unroll
        for (int t = 0; t < 16; ++t) {
            const int cc = t * 16 + col;
            bb[t] = bias[cc]; gm[t] = gamma[cc]; bt[t] = beta[cc];
        }
        const int rbase = blockIdx.x * 32 + wv * 16 + quad * 4;
        #pragma unroll
        for (int r = 0; r < 4; ++r) {
            const int row = rbase + r;
            float val[16], s1 = 0.f, s2 = 0.f;
            #pragma unroll
            for (int t = 0; t < 16; ++t) {
                float v = acc[t][r] + bb[t];
                if constexpr (EPI == 0) v += resid[(size_t)row * 256 + t * 16 + col];
                val[t] = v; s1 += v; s2 += v * v;
            }
            s1 += __shfl_xor(s1, 1); s1 += __shfl_xor(s1, 2);
            s1 += __shfl_xor(s1, 4); s1 += __shfl_xor(s1, 8);
            s2 += __shfl_xor(s2, 1); s2 += __shfl_xor(s2, 2);
            s2 += __shfl_xor(s2, 4); s2 += __shfl_xor(s2, 8);
            const float mu = s1 * (1.0f / 256.0f);
            const float rv = rsqrtf(s2 * (1.0f / 256.0f) - mu * mu + 1e-5f);
            #pragma unroll
            for (int t = 0; t < 16; ++t) {
                const float o = (val[t] - mu) * rv * gm[t] + bt[t];
                outf[(size_t)row * 256 + t * 16 + col] = o;
                outb[(size_t)row * 256 + t * 16 + col] = (__bf16)o;
            }
        }
    } else if constexpr (EPI == 1) {
        #pragma unroll
        for (int t = 0; t < 16; ++t) {
            const int cc = cg * 256 + t * 16 + col;
            const float bbv = bias[cc];
            #pragma unroll
            for (int r = 0; r < 4; ++r) {
                const int row = blockIdx.x * 32 + wv * 16 + quad * 4 + r;
                outb[(size_t)row * 512 + cc] = (__bf16)fmaxf(acc[t][r] + bbv, 0.f);
            }
        }
    } else {  // EPI == 2, QKV
        const float qs = (cg == 0) ? 0.17677669529663687f : 1.0f;
        #pragma unroll
        for (int t = 0; t < 16; ++t) {
            const int cc = t * 16 + col;
            const int h = cc >> 5, dh = cc & 31;
            const float bbv = bias[cg * 256 + cc];
            #pragma unroll
            for (int r = 0; r < 4; ++r) {
                const int n = n0 + quad * 4 + r;
                const __bf16 v = (__bf16)((acc[t][r] + bbv) * qs);
                if (cg == 0)
                    outb[(((size_t)(b * Hh + h)) * Nn + n) * DHc + dh] = v;
                else if (cg == 1)
                    outb2[(((size_t)(b * Hh + h)) * Nn + n) * DHc + dh] = v;
                else
                    outb3[(((size_t)(b * Hh + h)) * DHc + dh) * Nn + n] = v;
            }
        }
    }
}

// ---------------------------------------------------------------------------
// MFMA flash attention. Block = one (b,h) x 64 queries (4 waves x 16 q).
// ---------------------------------------------------------------------------
__global__ __launch_bounds__(256)
void attn_mfma(const __bf16* __restrict__ Qb, const __bf16* __restrict__ Kb,
               const __bf16* __restrict__ Vb, const unsigned short* __restrict__ MBu,
               __bf16* __restrict__ O)
{
    __shared__ __bf16 pbuf[4][16][72];
    const int tid = threadIdx.x;
    const int lane = tid & 63;
    const int wv = tid >> 6;
    const int col = lane & 15;
    const int quad = lane >> 4;
    const int bh = blockIdx.y;
    const int b = bh >> 3, h = bh & 7;
    const int q0 = blockIdx.x * 64 + wv * 16;
    const int hbit = (h < 2) ? 1 : (h < 6) ? 2 : 0;

    const bf16x8 qf = *(const bf16x8*)(Qb + ((size_t)bh * Nn + q0 + col) * DHc + quad * 8);

    f32x4 O0 = {0.f, 0.f, 0.f, 0.f}, O1 = {0.f, 0.f, 0.f, 0.f};
    float M[4], L[4];
    #pragma unroll
    for (int r = 0; r < 4; ++r) { M[r] = -INFINITY; L[r] = 0.0f; }

    const unsigned short* mrow = MBu + ((size_t)b << 18);
    __bf16* pw = &pbuf[wv][0][0];
    const __bf16* prd = &pbuf[wv][col][0];
    const f32x4 zf = {0.f, 0.f, 0.f, 0.f};

    for (int c = 0; c < 16; ++c) {
        const __bf16* kp = Kb + ((size_t)bh * Nn + c * 64 + col) * DHc + quad * 8;
        f32x4 S[4];
        #pragma unroll
        for (int t = 0; t < 4; ++t) {
            const bf16x8 kf = *(const bf16x8*)(kp + (size_t)t * 16 * DHc);
            S[t] = __builtin_amdgcn_mfma_f32_16x16x32_bf16(qf, kf, zf, 0, 0, 0);
        }
        if (hbit) {
            #pragma unroll
            for (int r = 0; r < 4; ++r) {
                const int q = q0 + quad * 4 + r;
                const unsigned short ms = mrow[((size_t)q << 8) + (c << 4) + col];
                if (!((ms      ) & hbit)) S[0][r] = -INFINITY;
                if (!((ms >>  4) & hbit)) S[1][r] = -INFINITY;
                if (!((ms >>  8) & hbit)) S[2][r] = -INFINITY;
                if (!((ms >> 12) & hbit)) S[3][r] = -INFINITY;
            }
        }
        float alpha[4];
        #pragma unroll
        for (int r = 0; r < 4; ++r) {
            float mx = fmaxf(fmaxf(S[0][r], S[1][r]), fmaxf(S[2][r], S[3][r]));
            mx = fmaxf(mx, __shfl_xor(mx, 1));
            mx = fmaxf(mx, __shfl_xor(mx, 2));
            mx = fmaxf(mx, __shfl_xor(mx, 4));
            mx = fmaxf(mx, __shfl_xor(mx, 8));
            const float Mnew = fmaxf(M[r], mx);
            alpha[r] = (Mnew == -INFINITY) ? 1.0f : __expf(M[r] - Mnew);
            float ps = 0.0f;
            #pragma unroll
            for (int t = 0; t < 4; ++t) {
                const float p = (S[t][r] == -INFINITY) ? 0.0f : __expf(S[t][r] - Mnew);
                S[t][r] = p;
                ps += p;
            }
            ps += __shfl_xor(ps, 1);
            ps += __shfl_xor(ps, 2);
            ps += __shfl_xor(ps, 4);
            ps += __shfl_xor(ps, 8);
            L[r] = L[r] * alpha[r] + ps;
            M[r] = Mnew;
        }
        #pragma unroll
        for (int r = 0; r < 4; ++r) {
            #pragma unroll
            for (int t = 0; t < 4; ++t)
                pw[(quad * 4 + r) * 72 + t * 16 + col] = (__bf16)S[t][r];
            O0[r] *= alpha[r];
            O1[r] *= alpha[r];
        }
        const __bf16* vp = Vb + ((size_t)bh * DHc) * Nn + c * 64 + quad * 8;
        #pragma unroll
        for (int kh = 0; kh < 2; ++kh) {
            const bf16x8 pf = *(const bf16x8*)(prd + kh * 32 + quad * 8);
            const bf16x8 v0 = *(const bf16x8*)(vp + (size_t)col * Nn + kh * 32);
            const bf16x8 v1 = *(const bf16x8*)(vp + (size_t)(col + 16) * Nn + kh * 32);
            O0 = __builtin_amdgcn_mfma_f32_16x16x32_bf16(pf, v0, O0, 0, 0, 0);
            O1 = __builtin_amdgcn_mfma_f32_16x16x32_bf16(pf, v1, O1, 0, 0, 0);
        }
    }
    #pragma unroll
    for (int r = 0; r < 4; ++r) {
        const float inv = 1.0f / L[r];
        const int q = q0 + quad * 4 + r;
        __bf16* op = O + ((size_t)q * Bb + b) * HIDc + h * DHc + col;
        op[0]  = (__bf16)(O0[r] * inv);
        op[16] = (__bf16)(O1[r] * inv);
    }
}

// ---------------------------------------------------------------------------
// Final: y = x[0] (tokens 0..7), batch-norm over B, scale/shift.
// ---------------------------------------------------------------------------
__global__ __launch_bounds__(256)
void final_bn(const float* __restrict__ x, const float* __restrict__ g,
              const float* __restrict__ bta, float* __restrict__ out)
{
    const int d = threadIdx.x;
    float y[8]; float mu = 0.0f;
    #pragma unroll
    for (int i = 0; i < 8; ++i) { y[i] = x[i * 256 + d]; mu += y[i]; }
    mu *= 0.125f;
    float var = 0.0f;
    #pragma unroll
    for (int i = 0; i < 8; ++i) { const float dd = y[i] - mu; var += dd * dd; }
    var *= 0.125f;
    const float r = rsqrtf(var + 1e-5f);
    const float gg = g[d], bb = bta[d];
    #pragma unroll
    for (int i = 0; i < 8; ++i) out[i * 256 + d] = (y[i] - mu) * r * gg + bb;
}

extern "C" void kernel_launch(void* const* d_in, const int* in_sizes, int n_in,
                              void* d_out, int out_size, void* d_ws, size_t ws_size,
                              hipStream_t stream)
{
    const float* nodes   = (const float*)d_in[0];
    const int*   dist    = (const int*)  d_in[1];
    const float* W_in    = (const float*)d_in[2];
    const float* b_in    = (const float*)d_in[3];
    const float* ln_in_g = (const float*)d_in[4];
    const float* ln_in_b = (const float*)d_in[5];
    const float* Wqkv    = (const float*)d_in[6];
    const float* bqkv    = (const float*)d_in[7];
    const float* Wo      = (const float*)d_in[8];
    const float* bo      = (const float*)d_in[9];
    const float* ln1_g   = (const float*)d_in[10];
    const float* ln1_b   = (const float*)d_in[11];
    const float* W1      = (const float*)d_in[12];
    const float* b1      = (const float*)d_in[13];
    const float* W2      = (const float*)d_in[14];
    const float* b2      = (const float*)d_in[15];
    const float* ln2_g   = (const float*)d_in[16];
    const float* ln2_b   = (const float*)d_in[17];
    const float* bn_g    = (const float*)d_in[18];
    const float* bn_b    = (const float*)d_in[19];

    // workspace (byte offsets), max 35913728 B = 34.25 MB:
    //   x    f32   0 .. 8M
    //   xb   bf16  8M .. 12M
    //   mb   u16   12M .. 16M
    //   wt   bf16  16M .. 18.25M
    //   qb   bf16  18.25 .. 22.25   (aliased by h1b / xin_b when dead)
    //   kb   bf16  22.25 .. 26.25   (aliased by h1b tail)
    //   vb   bf16  26.25 .. 30.25
    //   ob   bf16  30.25 .. 34.25
    char* ws = (char*)d_ws;
    float*  x    = (float*)(ws);
    __bf16* xb   = (__bf16*)(ws + 8388608);
    unsigned short* mb = (unsigned short*)(ws + 12582912);
    __bf16* wt   = (__bf16*)(ws + 16777216);
    __bf16* qb   = (__bf16*)(ws + 19136512);
    __bf16* kb   = (__bf16*)(ws + 23330816);
    __bf16* vb   = (__bf16*)(ws + 27525120);
    __bf16* ob   = (__bf16*)(ws + 31719424);
    __bf16* h1b  = qb;       // 8 MB, aliases qb+kb (dead during FFN)
    __bf16* xinb = qb;       // 4 MB, aliases qb (dead before qkv l0)

    // weight segment table (element offsets into wt)
    WCvtArgs wa;
    wa.src[0] = W_in;           wa.K[0] = 256; wa.M[0] = 256; wa.dstOff[0] = 0;
    wa.src[1] = Wqkv;           wa.K[1] = 256; wa.M[1] = 768; wa.dstOff[1] = 65536;
    wa.src[2] = Wqkv + 196608;  wa.K[2] = 256; wa.M[2] = 768; wa.dstOff[2] = 262144;
    wa.src[3] = Wo;             wa.K[3] = 256; wa.M[3] = 256; wa.dstOff[3] = 458752;
    wa.src[4] = Wo + 65536;     wa.K[4] = 256; wa.M[4] = 256; wa.dstOff[4] = 524288;
    wa.src[5] = W1;             wa.K[5] = 256; wa.M[5] = 512; wa.dstOff[5] = 589824;
    wa.src[6] = W1 + 131072;    wa.K[6] = 256; wa.M[6] = 512; wa.dstOff[6] = 720896;
    wa.src[7] = W2;             wa.K[7] = 512; wa.M[7] = 256; wa.dstOff[7] = 851968;
    wa.src[8] = W2 + 131072;    wa.K[8] = 512; wa.M[8] = 256; wa.dstOff[8] = 983040;
    int total_tiles = 0;
    for (int i = 0; i < 9; ++i) { wa.tiles[i] = (wa.K[i] >> 5) * (wa.M[i] >> 5); total_tiles += wa.tiles[i]; }

    wcvt_k<<<total_tiles, 256, 0, stream>>>(wa, wt);
    mask_k<<<8192, 256, 0, stream>>>(dist, mb);
    xin_k<<<4096, 256, 0, stream>>>(nodes, xinb);

    // x, xb = LN(xin @ W_in + b_in)
    dense_mfma<256, 3><<<dim3(256, 1), 128, 0, stream>>>(
        xinb, wt + 0, b_in, nullptr, ln_in_g, ln_in_b, x, xb, nullptr, nullptr);

    for (int l = 0; l < 2; ++l) {
        __bf16* wqkv_t = wt + (l == 0 ? 65536 : 262144);
        __bf16* wo_t   = wt + (l == 0 ? 458752 : 524288);
        __bf16* w1_t   = wt + (l == 0 ? 589824 : 720896);
        __bf16* w2_t   = wt + (l == 0 ? 851968 : 983040);

        // q (scaled), k, v^T bf16
        dense_mfma<256, 2><<<dim3(256, 3), 128, 0, stream>>>(
            xb, wqkv_t, bqkv + l * 768, nullptr, nullptr, nullptr,
            nullptr, qb, kb, vb);
        // attention -> ob bf16 (N,B,HID)
        attn_mfma<<<dim3(16, 64), 256, 0, stream>>>(qb, kb, vb, mb, ob);
        // x, xb = LN(x + ob @ Wo + bo)
        dense_mfma<256, 0><<<dim3(256, 1), 128, 0, stream>>>(
            ob, wo_t, bo + l * 256, x, ln1_g + l * 256, ln1_b + l * 256,
            x, xb, nullptr, nullptr);
        // h1b = relu(xb @ W1 + b1)  (bf16, M=512)
        dense_mfma<256, 1><<<dim3(256, 2), 128, 0, stream>>>(
            xb, w1_t, b1 + l * 512, nullptr, nullptr, nullptr,
            nullptr, h1b, nullptr, nullptr);
        // x, xb = LN(x + h1b @ W2 + b2)  (K=512)
        dense_mfma<512, 0><<<dim3(256, 1), 128, 0, stream>>>(
            h1b, w2_t, b2 + l * 256, x, ln2_g + l * 256, ln2_b + l * 256,
            x, xb, nullptr, nullptr);
    }

    final_bn<<<1, 256, 0, stream>>>(x, bn_g, bn_b, (float*)d_out);
}

// Round 4
// 346.373 us; speedup vs baseline: 5.4433x; 1.6832x over previous
//
#include <hip/hip_runtime.h>
#include <math.h>

// dims
constexpr int Nn = 1024, Bb = 8, HIDc = 256, Hh = 8, DHc = 32;

typedef __bf16 bf16x8 __attribute__((ext_vector_type(8)));
typedef float  f32x4  __attribute__((ext_vector_type(4)));

// ---------------------------------------------------------------------------
// Weight convert+transpose: Wt[m][k] = bf16(W[k][m]) for all 9 weight mats.
// ---------------------------------------------------------------------------
struct WCvtArgs {
    const float* src[9];
    int K[9], M[9], dstOff[9], tiles[9];
};

__global__ __launch_bounds__(256)
void wcvt_k(WCvtArgs a, __bf16* __restrict__ Wt)
{
    __shared__ float ts[32][33];
    int bid = blockIdx.x, i = 0;
    while (bid >= a.tiles[i]) { bid -= a.tiles[i]; ++i; }
    const int K = a.K[i], M = a.M[i];
    const int tilesM = M >> 5;
    const int m0 = (bid % tilesM) << 5, k0 = (bid / tilesM) << 5;
    const float* src = a.src[i];
    __bf16* dst = Wt + a.dstOff[i];
    const int tx = threadIdx.x & 31, ty = threadIdx.x >> 5;
    #pragma unroll
    for (int j = 0; j < 4; ++j) {
        const int row = ty + 8 * j;
        ts[row][tx] = src[(size_t)(k0 + row) * M + m0 + tx];
    }
    __syncthreads();
    #pragma unroll
    for (int j = 0; j < 4; ++j) {
        const int row = ty + 8 * j;
        dst[(size_t)(m0 + row) * K + k0 + tx] = (__bf16)ts[tx][row];
    }
}

// ---------------------------------------------------------------------------
// Mask precompute: 4-bit codes packed in ushort per (b,q,c,col).
// ---------------------------------------------------------------------------
__global__ __launch_bounds__(256)
void mask_k(const int* __restrict__ dist, unsigned short* __restrict__ mbu)
{
    const int idx = blockIdx.x * 256 + threadIdx.x;   // 2M entries
    const int col = idx & 15, c = (idx >> 4) & 15, q = (idx >> 8) & 1023, b = idx >> 18;
    const int* dp = dist + ((((size_t)b << 10) + q) << 10) + c * 64 + col;
    unsigned int us = 0;
    #pragma unroll
    for (int t = 0; t < 4; ++t) {
        const int d = dp[t * 16];
        const unsigned int code = (unsigned int)((d == 1 ? 1 : 0) | (d >= 1 ? 2 : 0));
        us |= code << (4 * t);
    }
    mbu[idx] = (unsigned short)us;
}

// ---------------------------------------------------------------------------
// Input prep: xinb = bf16(nodes + sinusoidal PE).
// ---------------------------------------------------------------------------
__global__ __launch_bounds__(256)
void xin_k(const float* __restrict__ nodes, __bf16* __restrict__ xinb)
{
    const int idx = blockIdx.x * 256 + threadIdx.x;   // 1M threads
    const int token = idx >> 7, k2 = (idx & 127) * 2;
    const int n = token >> 3;
    const float e = (float)k2 * (1.0f / 256.0f);
    const float freq = exp2f(-13.287712379549449f * e);   // 10000^-e
    const float ang = (float)n * freq;
    const float2 nd = *(const float2*)(nodes + (size_t)token * 256 + k2);
    __bf16 o0 = (__bf16)(nd.x + sinf(ang));
    __bf16 o1 = (__bf16)(nd.y + cosf(ang));
    __bf16* p = xinb + (size_t)token * 256 + k2;
    p[0] = o0; p[1] = o1;
}

// ---------------------------------------------------------------------------
// MFMA dense with LDS weight staging.
// Block = 256 threads = 4 waves = 2 row-tiles x 2 col-halves (128 cols each).
// Weights staged per 64-k chunk into LDS (padded rows, ds_read_b128).
// EPI: 0 = LN(resid + y) -> fp32 + bf16   3 = LN(y) -> fp32 + bf16
//      1 = ReLU -> bf16 (M=512 via grid.y)
//      2 = QKV: grid.y = 0/1/2 -> q(scaled)/k/v^T, n-major row mapping
// ---------------------------------------------------------------------------
template<int K, int EPI>
__global__ __launch_bounds__(256, 4)
void dense_mfma(const __bf16* __restrict__ Xb, const __bf16* __restrict__ Wt,
                const float* __restrict__ bias, const float* __restrict__ resid,
                const float* __restrict__ gamma, const float* __restrict__ beta,
                float* __restrict__ outf, __bf16* __restrict__ outb,
                __bf16* __restrict__ outb2, __bf16* __restrict__ outb3)
{
    constexpr int KC = 64;           // k per staged chunk
    constexpr int NCH = K / KC;
    __shared__ __bf16 wlds[256][72]; // 72: 16B-aligned rows, spreads banks
    __shared__ float red[2][2][16][2];

    const int tid = threadIdx.x;
    const int lane = tid & 63;
    const int wv = tid >> 6;         // 0..3
    const int rt = wv >> 1;          // row-tile within block
    const int ch = wv & 1;           // column half
    const int col = lane & 15;
    const int quad = lane >> 4;
    const int cg = blockIdx.y;

    int rowA, n0 = 0, b = 0;
    if constexpr (EPI == 2) {
        b = blockIdx.x & 7;
        n0 = (blockIdx.x >> 3) * 32 + rt * 16;
        rowA = (n0 + col) * 8 + b;
    } else {
        rowA = blockIdx.x * 32 + rt * 16 + col;
    }

    const __bf16* wsrc = Wt + (size_t)(cg * 256) * K;

    f32x4 acc[8];
    #pragma unroll
    for (int t = 0; t < 8; ++t) acc[t] = (f32x4){0.f, 0.f, 0.f, 0.f};

    for (int ck = 0; ck < NCH; ++ck) {
        if (ck) __syncthreads();
        // cooperative stage: 256 rows x 64 k (2048 bf16x8 vectors, 8/thread)
        #pragma unroll
        for (int i = 0; i < 8; ++i) {
            const int v = i * 256 + tid;
            const int m = v >> 3, kv = v & 7;
            *(bf16x8*)&wlds[m][kv * 8] =
                *(const bf16x8*)(wsrc + (size_t)m * K + ck * KC + kv * 8);
        }
        __syncthreads();
        bf16x8 af[2];
        #pragma unroll
        for (int kc = 0; kc < 2; ++kc)
            af[kc] = *(const bf16x8*)(Xb + (size_t)rowA * K + ck * KC + kc * 32 + quad * 8);
        #pragma unroll
        for (int t = 0; t < 8; ++t) {
            #pragma unroll
            for (int kc = 0; kc < 2; ++kc) {
                const bf16x8 bfr = *(const bf16x8*)(&wlds[ch * 128 + t * 16 + col][kc * 32 + quad * 8]);
                acc[t] = __builtin_amdgcn_mfma_f32_16x16x32_bf16(af[kc], bfr, acc[t], 0, 0, 0);
            }
        }
    }

    if constexpr (EPI == 0 || EPI == 3) {
        float bb[8], gm[8], bt[8];
        #pragma unroll
        for (int t = 0; t < 8; ++t) {
            const int cc = ch * 128 + t * 16 + col;
            bb[t] = bias[cc]; gm[t] = gamma[cc]; bt[t] = beta[cc];
        }
        const int rbase = blockIdx.x * 32 + rt * 16 + quad * 4;
        float val[4][8];
        #pragma unroll
        for (int r = 0; r < 4; ++r) {
            float s1 = 0.f, s2 = 0.f;
            #pragma unroll
            for (int t = 0; t < 8; ++t) {
                float v = acc[t][r] + bb[t];
                if constexpr (EPI == 0)
                    v += resid[(size_t)(rbase + r) * 256 + ch * 128 + t * 16 + col];
                val[r][t] = v; s1 += v; s2 += v * v;
            }
            s1 += __shfl_xor(s1, 1); s1 += __shfl_xor(s1, 2);
            s1 += __shfl_xor(s1, 4); s1 += __shfl_xor(s1, 8);
            s2 += __shfl_xor(s2, 1); s2 += __shfl_xor(s2, 2);
            s2 += __shfl_xor(s2, 4); s2 += __shfl_xor(s2, 8);
            if (col == 0) {
                red[rt][ch][quad * 4 + r][0] = s1;
                red[rt][ch][quad * 4 + r][1] = s2;
            }
        }
        __syncthreads();
        #pragma unroll
        for (int r = 0; r < 4; ++r) {
            const int qr = quad * 4 + r;
            const float s1 = red[rt][0][qr][0] + red[rt][1][qr][0];
            const float s2 = red[rt][0][qr][1] + red[rt][1][qr][1];
            const float mu = s1 * (1.0f / 256.0f);
            const float rv = rsqrtf(s2 * (1.0f / 256.0f) - mu * mu + 1e-5f);
            const int row = rbase + r;
            #pragma unroll
            for (int t = 0; t < 8; ++t) {
                const float o = (val[r][t] - mu) * rv * gm[t] + bt[t];
                outf[(size_t)row * 256 + ch * 128 + t * 16 + col] = o;
                outb[(size_t)row * 256 + ch * 128 + t * 16 + col] = (__bf16)o;
            }
        }
    } else if constexpr (EPI == 1) {
        #pragma unroll
        for (int t = 0; t < 8; ++t) {
            const int cc = cg * 256 + ch * 128 + t * 16 + col;
            const float bbv = bias[cc];
            #pragma unroll
            for (int r = 0; r < 4; ++r) {
                const int row = blockIdx.x * 32 + rt * 16 + quad * 4 + r;
                outb[(size_t)row * 512 + cc] = (__bf16)fmaxf(acc[t][r] + bbv, 0.f);
            }
        }
    } else {  // EPI == 2, QKV
        const float qs = (cg == 0) ? 0.17677669529663687f : 1.0f;
        #pragma unroll
        for (int t = 0; t < 8; ++t) {
            const int cc = ch * 128 + t * 16 + col;
            const int h = cc >> 5, dh = cc & 31;
            const float bbv = bias[cg * 256 + cc];
            #pragma unroll
            for (int r = 0; r < 4; ++r) {
                const int n = n0 + quad * 4 + r;
                const __bf16 v = (__bf16)((acc[t][r] + bbv) * qs);
                if (cg == 0)
                    outb[(((size_t)(b * Hh + h)) * Nn + n) * DHc + dh] = v;
                else if (cg == 1)
                    outb2[(((size_t)(b * Hh + h)) * Nn + n) * DHc + dh] = v;
                else
                    outb3[(((size_t)(b * Hh + h)) * DHc + dh) * Nn + n] = v;
            }
        }
    }
}

// ---------------------------------------------------------------------------
// MFMA flash attention. Block = one (b,h) x 64 queries (4 waves x 16 q).
// ---------------------------------------------------------------------------
__global__ __launch_bounds__(256)
void attn_mfma(const __bf16* __restrict__ Qb, const __bf16* __restrict__ Kb,
               const __bf16* __restrict__ Vb, const unsigned short* __restrict__ MBu,
               __bf16* __restrict__ O)
{
    __shared__ __bf16 pbuf[4][16][72];
    const int tid = threadIdx.x;
    const int lane = tid & 63;
    const int wv = tid >> 6;
    const int col = lane & 15;
    const int quad = lane >> 4;
    const int bh = blockIdx.y;
    const int b = bh >> 3, h = bh & 7;
    const int q0 = blockIdx.x * 64 + wv * 16;
    const int hbit = (h < 2) ? 1 : (h < 6) ? 2 : 0;

    const bf16x8 qf = *(const bf16x8*)(Qb + ((size_t)bh * Nn + q0 + col) * DHc + quad * 8);

    f32x4 O0 = {0.f, 0.f, 0.f, 0.f}, O1 = {0.f, 0.f, 0.f, 0.f};
    float M[4], L[4];
    #pragma unroll
    for (int r = 0; r < 4; ++r) { M[r] = -INFINITY; L[r] = 0.0f; }

    const unsigned short* mrow = MBu + ((size_t)b << 18);
    __bf16* pw = &pbuf[wv][0][0];
    const __bf16* prd = &pbuf[wv][col][0];
    const f32x4 zf = {0.f, 0.f, 0.f, 0.f};

    for (int c = 0; c < 16; ++c) {
        const __bf16* kp = Kb + ((size_t)bh * Nn + c * 64 + col) * DHc + quad * 8;
        f32x4 S[4];
        #pragma unroll
        for (int t = 0; t < 4; ++t) {
            const bf16x8 kf = *(const bf16x8*)(kp + (size_t)t * 16 * DHc);
            S[t] = __builtin_amdgcn_mfma_f32_16x16x32_bf16(qf, kf, zf, 0, 0, 0);
        }
        if (hbit) {
            #pragma unroll
            for (int r = 0; r < 4; ++r) {
                const int q = q0 + quad * 4 + r;
                const unsigned short ms = mrow[((size_t)q << 8) + (c << 4) + col];
                if (!((ms      ) & hbit)) S[0][r] = -INFINITY;
                if (!((ms >>  4) & hbit)) S[1][r] = -INFINITY;
                if (!((ms >>  8) & hbit)) S[2][r] = -INFINITY;
                if (!((ms >> 12) & hbit)) S[3][r] = -INFINITY;
            }
        }
        float alpha[4];
        #pragma unroll
        for (int r = 0; r < 4; ++r) {
            float mx = fmaxf(fmaxf(S[0][r], S[1][r]), fmaxf(S[2][r], S[3][r]));
            mx = fmaxf(mx, __shfl_xor(mx, 1));
            mx = fmaxf(mx, __shfl_xor(mx, 2));
            mx = fmaxf(mx, __shfl_xor(mx, 4));
            mx = fmaxf(mx, __shfl_xor(mx, 8));
            const float Mnew = fmaxf(M[r], mx);
            alpha[r] = (Mnew == -INFINITY) ? 1.0f : __expf(M[r] - Mnew);
            float ps = 0.0f;
            #pragma unroll
            for (int t = 0; t < 4; ++t) {
                const float p = (S[t][r] == -INFINITY) ? 0.0f : __expf(S[t][r] - Mnew);
                S[t][r] = p;
                ps += p;
            }
            ps += __shfl_xor(ps, 1);
            ps += __shfl_xor(ps, 2);
            ps += __shfl_xor(ps, 4);
            ps += __shfl_xor(ps, 8);
            L[r] = L[r] * alpha[r] + ps;
            M[r] = Mnew;
        }
        #pragma unroll
        for (int r = 0; r < 4; ++r) {
            #pragma unroll
            for (int t = 0; t < 4; ++t)
                pw[(quad * 4 + r) * 72 + t * 16 + col] = (__bf16)S[t][r];
            O0[r] *= alpha[r];
            O1[r] *= alpha[r];
        }
        const __bf16* vp = Vb + ((size_t)bh * DHc) * Nn + c * 64 + quad * 8;
        #pragma unroll
        for (int kh = 0; kh < 2; ++kh) {
            const bf16x8 pf = *(const bf16x8*)(prd + kh * 32 + quad * 8);
            const bf16x8 v0 = *(const bf16x8*)(vp + (size_t)col * Nn + kh * 32);
            const bf16x8 v1 = *(const bf16x8*)(vp + (size_t)(col + 16) * Nn + kh * 32);
            O0 = __builtin_amdgcn_mfma_f32_16x16x32_bf16(pf, v0, O0, 0, 0, 0);
            O1 = __builtin_amdgcn_mfma_f32_16x16x32_bf16(pf, v1, O1, 0, 0, 0);
        }
    }
    #pragma unroll
    for (int r = 0; r < 4; ++r) {
        const float inv = 1.0f / L[r];
        const int q = q0 + quad * 4 + r;
        __bf16* op = O + ((size_t)q * Bb + b) * HIDc + h * DHc + col;
        op[0]  = (__bf16)(O0[r] * inv);
        op[16] = (__bf16)(O1[r] * inv);
    }
}

// ---------------------------------------------------------------------------
// Final: y = x[0] (tokens 0..7), batch-norm over B, scale/shift.
// ---------------------------------------------------------------------------
__global__ __launch_bounds__(256)
void final_bn(const float* __restrict__ x, const float* __restrict__ g,
              const float* __restrict__ bta, float* __restrict__ out)
{
    const int d = threadIdx.x;
    float y[8]; float mu = 0.0f;
    #pragma unroll
    for (int i = 0; i < 8; ++i) { y[i] = x[i * 256 + d]; mu += y[i]; }
    mu *= 0.125f;
    float var = 0.0f;
    #pragma unroll
    for (int i = 0; i < 8; ++i) { const float dd = y[i] - mu; var += dd * dd; }
    var *= 0.125f;
    const float r = rsqrtf(var + 1e-5f);
    const float gg = g[d], bb = bta[d];
    #pragma unroll
    for (int i = 0; i < 8; ++i) out[i * 256 + d] = (y[i] - mu) * r * gg + bb;
}

extern "C" void kernel_launch(void* const* d_in, const int* in_sizes, int n_in,
                              void* d_out, int out_size, void* d_ws, size_t ws_size,
                              hipStream_t stream)
{
    const float* nodes   = (const float*)d_in[0];
    const int*   dist    = (const int*)  d_in[1];
    const float* W_in    = (const float*)d_in[2];
    const float* b_in    = (const float*)d_in[3];
    const float* ln_in_g = (const float*)d_in[4];
    const float* ln_in_b = (const float*)d_in[5];
    const float* Wqkv    = (const float*)d_in[6];
    const float* bqkv    = (const float*)d_in[7];
    const float* Wo      = (const float*)d_in[8];
    const float* bo      = (const float*)d_in[9];
    const float* ln1_g   = (const float*)d_in[10];
    const float* ln1_b   = (const float*)d_in[11];
    const float* W1      = (const float*)d_in[12];
    const float* b1      = (const float*)d_in[13];
    const float* W2      = (const float*)d_in[14];
    const float* b2      = (const float*)d_in[15];
    const float* ln2_g   = (const float*)d_in[16];
    const float* ln2_b   = (const float*)d_in[17];
    const float* bn_g    = (const float*)d_in[18];
    const float* bn_b    = (const float*)d_in[19];

    // workspace (byte offsets), max 34.25 MB
    char* ws = (char*)d_ws;
    float*  x    = (float*)(ws);
    __bf16* xb   = (__bf16*)(ws + 8388608);
    unsigned short* mb = (unsigned short*)(ws + 12582912);
    __bf16* wt   = (__bf16*)(ws + 16777216);
    __bf16* qb   = (__bf16*)(ws + 19136512);
    __bf16* kb   = (__bf16*)(ws + 23330816);
    __bf16* vb   = (__bf16*)(ws + 27525120);
    __bf16* ob   = (__bf16*)(ws + 31719424);
    __bf16* h1b  = qb;       // 8 MB, aliases qb+kb (dead during FFN)
    __bf16* xinb = qb;       // 4 MB, aliases qb (dead before qkv l0)

    WCvtArgs wa;
    wa.src[0] = W_in;           wa.K[0] = 256; wa.M[0] = 256; wa.dstOff[0] = 0;
    wa.src[1] = Wqkv;           wa.K[1] = 256; wa.M[1] = 768; wa.dstOff[1] = 65536;
    wa.src[2] = Wqkv + 196608;  wa.K[2] = 256; wa.M[2] = 768; wa.dstOff[2] = 262144;
    wa.src[3] = Wo;             wa.K[3] = 256; wa.M[3] = 256; wa.dstOff[3] = 458752;
    wa.src[4] = Wo + 65536;     wa.K[4] = 256; wa.M[4] = 256; wa.dstOff[4] = 524288;
    wa.src[5] = W1;             wa.K[5] = 256; wa.M[5] = 512; wa.dstOff[5] = 589824;
    wa.src[6] = W1 + 131072;    wa.K[6] = 256; wa.M[6] = 512; wa.dstOff[6] = 720896;
    wa.src[7] = W2;             wa.K[7] = 512; wa.M[7] = 256; wa.dstOff[7] = 851968;
    wa.src[8] = W2 + 131072;    wa.K[8] = 512; wa.M[8] = 256; wa.dstOff[8] = 983040;
    int total_tiles = 0;
    for (int i = 0; i < 9; ++i) { wa.tiles[i] = (wa.K[i] >> 5) * (wa.M[i] >> 5); total_tiles += wa.tiles[i]; }

    wcvt_k<<<total_tiles, 256, 0, stream>>>(wa, wt);
    mask_k<<<8192, 256, 0, stream>>>(dist, mb);
    xin_k<<<4096, 256, 0, stream>>>(nodes, xinb);

    // x, xb = LN(xin @ W_in + b_in)
    dense_mfma<256, 3><<<dim3(256, 1), 256, 0, stream>>>(
        xinb, wt + 0, b_in, nullptr, ln_in_g, ln_in_b, x, xb, nullptr, nullptr);

    for (int l = 0; l < 2; ++l) {
        __bf16* wqkv_t = wt + (l == 0 ? 65536 : 262144);
        __bf16* wo_t   = wt + (l == 0 ? 458752 : 524288);
        __bf16* w1_t   = wt + (l == 0 ? 589824 : 720896);
        __bf16* w2_t   = wt + (l == 0 ? 851968 : 983040);

        // q (scaled), k, v^T bf16
        dense_mfma<256, 2><<<dim3(256, 3), 256, 0, stream>>>(
            xb, wqkv_t, bqkv + l * 768, nullptr, nullptr, nullptr,
            nullptr, qb, kb, vb);
        // attention -> ob bf16 (N,B,HID)
        attn_mfma<<<dim3(16, 64), 256, 0, stream>>>(qb, kb, vb, mb, ob);
        // x, xb = LN(x + ob @ Wo + bo)
        dense_mfma<256, 0><<<dim3(256, 1), 256, 0, stream>>>(
            ob, wo_t, bo + l * 256, x, ln1_g + l * 256, ln1_b + l * 256,
            x, xb, nullptr, nullptr);
        // h1b = relu(xb @ W1 + b1)  (bf16, M=512)
        dense_mfma<256, 1><<<dim3(256, 2), 256, 0, stream>>>(
            xb, w1_t, b1 + l * 512, nullptr, nullptr, nullptr,
            nullptr, h1b, nullptr, nullptr);
        // x, xb = LN(x + h1b @ W2 + b2)  (K=512)
        dense_mfma<512, 0><<<dim3(256, 1), 256, 0, stream>>>(
            h1b, w2_t, b2 + l * 256, x, ln2_g + l * 256, ln2_b + l * 256,
            x, xb, nullptr, nullptr);
    }

    final_bn<<<1, 256, 0, stream>>>(x, bn_g, bn_b, (float*)d_out);
}